// Round 1
// baseline (233.007 us; speedup 1.0000x reference)
//
#include <hip/hip_runtime.h>
#include <stdint.h>

// Problem constants: B=8, S=2048, D=256, DK=DV=128
typedef float    f32x4 __attribute__((ext_vector_type(4)));
typedef _Float16 f16x8 __attribute__((ext_vector_type(8)));
typedef _Float16 f16x4 __attribute__((ext_vector_type(4)));
typedef unsigned int u32x4 __attribute__((ext_vector_type(4)));

__device__ __forceinline__ f32x4 mfma16(f16x8 a, f16x8 b, f32x4 c) {
    return __builtin_amdgcn_mfma_f32_16x16x32_f16(a, b, c, 0, 0, 0);
}

// ---------------------------------------------------------------------------
// Kernel 0: transpose+convert the three weight matrices W[256][128] (f32)
// into Wt[w][n][k] = [3][128][256] f16 so B-fragments read contiguously.
// ---------------------------------------------------------------------------
__global__ void prep_weights(const float* __restrict__ Wq,
                             const float* __restrict__ Wk,
                             const float* __restrict__ Wv,
                             _Float16* __restrict__ wt) {
    int id = blockIdx.x * 256 + threadIdx.x;   // 0 .. 3*128*256-1
    int w   = id >> 15;                        // which weight
    int rem = id & 32767;
    int n   = rem >> 8;                        // 0..127 (output col)
    int k   = rem & 255;                       // 0..255 (input dim)
    const float* W = (w == 0) ? Wq : (w == 1) ? Wk : Wv;
    wt[id] = (_Float16)W[k * 128 + n];
}

// ---------------------------------------------------------------------------
// Kernel 1: projections. Y = X[16384,256] @ W[256,128] + b, f16 MFMA,
// fp32 accumulate. mode 0: q (scaled by 1/sqrt(128)*log2e), row-major.
// mode 1: k row-major. mode 2: v stored TRANSPOSED per batch: vt[b][dv][s].
// Block: 256 threads (4 waves), 64 rows x 128 cols per block.
// ---------------------------------------------------------------------------
__global__ __launch_bounds__(256) void proj_kernel(
    const float* __restrict__ xq, const float* __restrict__ xk,
    const float* __restrict__ xv, const _Float16* __restrict__ wt,
    const float* __restrict__ bq, const float* __restrict__ bk,
    const float* __restrict__ bv,
    _Float16* __restrict__ qo, _Float16* __restrict__ ko,
    _Float16* __restrict__ vt)
{
    const int mode = blockIdx.y;
    const int row0 = blockIdx.x * 64;
    const float*    X    = mode == 0 ? xq : mode == 1 ? xk : xv;
    const float*    bias = mode == 0 ? bq : mode == 1 ? bk : bv;
    const _Float16* W    = wt + mode * 32768;

    // +8 pad per row -> 2-way LDS bank aliasing only (free)
    __shared__ __align__(16) _Float16 Xs[64 * 40];
    __shared__ __align__(16) _Float16 Ws[128 * 40];

    const int tid  = threadIdx.x;
    const int wave = tid >> 6, lane = tid & 63;
    const int ln   = lane & 15, qd = lane >> 4;

    f32x4 acc[8];
    #pragma unroll
    for (int i = 0; i < 8; i++) acc[i] = (f32x4){0.f, 0.f, 0.f, 0.f};

    for (int kk = 0; kk < 8; kk++) {          // K = 256 in steps of 32
        const int k0 = kk * 32;
        __syncthreads();
        // stage X tile [64][32] f32 -> f16 LDS (vectorized float4)
        #pragma unroll
        for (int i = tid; i < 512; i += 256) {
            int r = i >> 3, c = i & 7;
            f32x4 d = *(const f32x4*)(X + (size_t)(row0 + r) * 256 + k0 + c * 4);
            f16x4 h;
            h[0] = (_Float16)d[0]; h[1] = (_Float16)d[1];
            h[2] = (_Float16)d[2]; h[3] = (_Float16)d[3];
            *(f16x4*)&Xs[r * 40 + c * 4] = h;
        }
        // stage Wt tile [128][32] f16 (16B vector copies)
        #pragma unroll
        for (int i = tid; i < 512; i += 256) {
            int n = i >> 2, c = i & 3;
            *(u32x4*)&Ws[n * 40 + c * 8] =
                *(const u32x4*)(W + n * 256 + k0 + c * 8);
        }
        __syncthreads();
        // wave handles rows wave*16..+15, all 8 column tiles
        f16x8 af = *(const f16x8*)&Xs[(wave * 16 + ln) * 40 + qd * 8];
        #pragma unroll
        for (int nt = 0; nt < 8; nt++) {
            f16x8 bf = *(const f16x8*)&Ws[(nt * 16 + ln) * 40 + qd * 8];
            acc[nt] = mfma16(af, bf, acc[nt]);
        }
    }

    // epilogue: add bias; q additionally folded with 1/sqrt(128)*log2(e)
    const float SC = 0.08838834764831845f * 1.4426950408889634f;
    #pragma unroll
    for (int nt = 0; nt < 8; nt++) {
        int col = nt * 16 + ln;
        float bb = bias[col];
        #pragma unroll
        for (int r = 0; r < 4; r++) {
            int row = row0 + wave * 16 + qd * 4 + r;   // C/D: row=(lane>>4)*4+r
            float val = acc[nt][r] + bb;
            if (mode == 0) {
                qo[(size_t)row * 128 + col] = (_Float16)(val * SC);
            } else if (mode == 1) {
                ko[(size_t)row * 128 + col] = (_Float16)val;
            } else {
                int b = row >> 11, s = row & 2047;
                vt[((size_t)(b * 128 + col)) * 2048 + s] = (_Float16)val;
            }
        }
    }
}

// ---------------------------------------------------------------------------
// Kernel 2: flash-style attention. Block = 64 Q rows (4 waves x 16 rows),
// iterate keys in tiles of 64. Q pre-scaled so exp2f is the softmax exp.
// Grid (32, 8) = 256 blocks.
// ---------------------------------------------------------------------------
__global__ __launch_bounds__(256) void attn_kernel(
    const _Float16* __restrict__ qp, const _Float16* __restrict__ kp,
    const _Float16* __restrict__ vtp, float* __restrict__ out)
{
    const int b  = blockIdx.y;
    const int q0 = blockIdx.x * 64;
    const int tid  = threadIdx.x;
    const int wave = tid >> 6, lane = tid & 63;
    const int ln   = lane & 15, qd = lane >> 4;

    __shared__ __align__(16) _Float16 Ks[64 * 136];   // K tile [s][dk], +8 pad
    __shared__ __align__(16) _Float16 Vs[128 * 72];   // V^T tile [dv][s], +8 pad
    __shared__ __align__(16) _Float16 Ps[4 * 16 * 72];// per-wave P [16][64], +8

    // persistent Q fragments: wave's 16 rows, K=128 -> 4 k-steps
    const _Float16* qrow =
        qp + (size_t)(b * 2048 + q0 + wave * 16 + ln) * 128 + qd * 8;
    f16x8 qf[4];
    #pragma unroll
    for (int c = 0; c < 4; c++) qf[c] = *(const f16x8*)(qrow + c * 32);

    f32x4 o[8];
    #pragma unroll
    for (int i = 0; i < 8; i++) o[i] = (f32x4){0.f, 0.f, 0.f, 0.f};
    float m_run[4] = {-1e30f, -1e30f, -1e30f, -1e30f};
    float l_run[4] = {0.f, 0.f, 0.f, 0.f};

    const _Float16* kbase = kp + (size_t)b * 2048 * 128;
    const _Float16* vbase = vtp + (size_t)b * 128 * 2048;

    for (int kt = 0; kt < 32; kt++) {
        __syncthreads();
        // stage K tile [64][128] f16
        const _Float16* ks = kbase + kt * 64 * 128;
        #pragma unroll
        for (int i = tid; i < 1024; i += 256) {
            int r = i >> 4, c = i & 15;
            *(u32x4*)&Ks[r * 136 + c * 8] = *(const u32x4*)(ks + r * 128 + c * 8);
        }
        // stage V^T tile [128][64] f16
        const _Float16* vs = vbase + kt * 64;
        #pragma unroll
        for (int i = tid; i < 1024; i += 256) {
            int r = i >> 3, c = i & 7;
            *(u32x4*)&Vs[r * 72 + c * 8] =
                *(const u32x4*)(vs + (size_t)r * 2048 + c * 8);
        }
        __syncthreads();

        // S = Q K^T  (log2-domain: scale*log2e folded into q)
        f32x4 sc[4];
        #pragma unroll
        for (int st = 0; st < 4; st++) {
            sc[st] = (f32x4){0.f, 0.f, 0.f, 0.f};
            int base = (st * 16 + ln) * 136 + qd * 8;
            #pragma unroll
            for (int c = 0; c < 4; c++) {
                f16x8 kf = *(const f16x8*)&Ks[base + c * 32];
                sc[st] = mfma16(qf[c], kf, sc[st]);
            }
        }

        // online softmax (rows = qd*4+r, cols spread over 16 lanes)
        float mnew[4], alpha[4];
        #pragma unroll
        for (int r = 0; r < 4; r++) {
            float t = fmaxf(fmaxf(sc[0][r], sc[1][r]), fmaxf(sc[2][r], sc[3][r]));
            t = fmaxf(t, __shfl_xor(t, 1));
            t = fmaxf(t, __shfl_xor(t, 2));
            t = fmaxf(t, __shfl_xor(t, 4));
            t = fmaxf(t, __shfl_xor(t, 8));
            mnew[r]  = fmaxf(m_run[r], t);
            alpha[r] = exp2f(m_run[r] - mnew[r]);
        }
        #pragma unroll
        for (int st = 0; st < 4; st++)
            #pragma unroll
            for (int r = 0; r < 4; r++) {
                float p = exp2f(sc[st][r] - mnew[r]);
                sc[st][r] = p;
                // C-layout -> LDS [row][col] for A-layout re-read (per-wave)
                Ps[wave * 1152 + (qd * 4 + r) * 72 + st * 16 + ln] = (_Float16)p;
            }
        #pragma unroll
        for (int r = 0; r < 4; r++) {
            float s = sc[0][r] + sc[1][r] + sc[2][r] + sc[3][r];
            s += __shfl_xor(s, 1); s += __shfl_xor(s, 2);
            s += __shfl_xor(s, 4); s += __shfl_xor(s, 8);
            l_run[r] = l_run[r] * alpha[r] + s;
            m_run[r] = mnew[r];
        }
        #pragma unroll
        for (int dt = 0; dt < 8; dt++)
            #pragma unroll
            for (int r = 0; r < 4; r++) o[dt][r] *= alpha[r];

        // O += P V   (P from per-wave LDS as A-frags, V^T as B-frags)
        #pragma unroll
        for (int c = 0; c < 2; c++) {
            f16x8 pf = *(const f16x8*)&Ps[wave * 1152 + ln * 72 + c * 32 + qd * 8];
            #pragma unroll
            for (int dt = 0; dt < 8; dt++) {
                f16x8 vf = *(const f16x8*)&Vs[(dt * 16 + ln) * 72 + c * 32 + qd * 8];
                o[dt] = mfma16(pf, vf, o[dt]);
            }
        }
    }

    // epilogue: O / l
    float inv[4];
    #pragma unroll
    for (int r = 0; r < 4; r++) inv[r] = 1.0f / l_run[r];
    float* orow = out + (size_t)(b * 2048 + q0 + wave * 16) * 128;
    #pragma unroll
    for (int dt = 0; dt < 8; dt++)
        #pragma unroll
        for (int r = 0; r < 4; r++)
            orow[(size_t)(qd * 4 + r) * 128 + dt * 16 + ln] = o[dt][r] * inv[r];
}

// ---------------------------------------------------------------------------
extern "C" void kernel_launch(void* const* d_in, const int* in_sizes, int n_in,
                              void* d_out, int out_size, void* d_ws, size_t ws_size,
                              hipStream_t stream) {
    const float* xq = (const float*)d_in[0];
    const float* xk = (const float*)d_in[1];
    const float* xv = (const float*)d_in[2];
    const float* Wq = (const float*)d_in[3];
    const float* bq = (const float*)d_in[4];
    const float* Wk = (const float*)d_in[5];
    const float* bk = (const float*)d_in[6];
    const float* Wv = (const float*)d_in[7];
    const float* bv = (const float*)d_in[8];
    float* out = (float*)d_out;

    // workspace layout (f16): Wt 3*32768, q 16384*128, k 16384*128, vt 8*128*2048
    char* ws = (char*)d_ws;
    _Float16* wt = (_Float16*)ws;                              // 196608 B
    _Float16* qo = (_Float16*)(ws + 196608);                   // 4 MB
    _Float16* ko = (_Float16*)(ws + 196608 + 4194304);         // 4 MB
    _Float16* vt = (_Float16*)(ws + 196608 + 8388608);         // 4 MB

    hipLaunchKernelGGL(prep_weights, dim3(384), dim3(256), 0, stream,
                       Wq, Wk, Wv, wt);
    hipLaunchKernelGGL(proj_kernel, dim3(256, 3), dim3(256), 0, stream,
                       xq, xk, xv, wt, bq, bk, bv, qo, ko, vt);
    hipLaunchKernelGGL(attn_kernel, dim3(32, 8), dim3(256), 0, stream,
                       qo, ko, vt, out);
}

// Round 2
// 189.665 us; speedup vs baseline: 1.2285x; 1.2285x over previous
//
#include <hip/hip_runtime.h>
#include <stdint.h>

// Problem constants: B=8, S=2048, D=256, DK=DV=128
typedef float    f32x4 __attribute__((ext_vector_type(4)));
typedef _Float16 f16x8 __attribute__((ext_vector_type(8)));
typedef _Float16 f16x4 __attribute__((ext_vector_type(4)));
typedef unsigned int u32x4 __attribute__((ext_vector_type(4)));

#define SPLIT 4   // KV splits per (batch, q-tile); 2048/SPLIT = 512 keys/block

__device__ __forceinline__ f32x4 mfma16(f16x8 a, f16x8 b, f32x4 c) {
    return __builtin_amdgcn_mfma_f32_16x16x32_f16(a, b, c, 0, 0, 0);
}

// ---------------------------------------------------------------------------
// Kernel 0: transpose+convert W[256][128] f32 -> Wt[w][n][k]=[3][128][256] f16
// via LDS 64x64 tiles: coalesced global reads AND writes.
// Grid: 24 blocks (3 matrices x 4 k-tiles x 2 n-tiles), 256 threads.
// ---------------------------------------------------------------------------
__global__ __launch_bounds__(256) void prep_weights(
    const float* __restrict__ Wq, const float* __restrict__ Wk,
    const float* __restrict__ Wv, _Float16* __restrict__ wt) {
    __shared__ float Ls[64 * 65];
    const int bx = blockIdx.x;
    const int w  = bx >> 3, t = bx & 7;
    const int k0 = (t >> 1) * 64, n0 = (t & 1) * 64;
    const float* W = (w == 0) ? Wq : (w == 1) ? Wk : Wv;
    const int tid = threadIdx.x;
    #pragma unroll
    for (int i = 0; i < 16; i++) {
        int idx = i * 256 + tid;
        int r = idx >> 6, c = idx & 63;              // r: k-offset, c: n-offset
        Ls[r * 65 + c] = W[(k0 + r) * 128 + n0 + c];
    }
    __syncthreads();
    #pragma unroll
    for (int i = 0; i < 16; i++) {
        int idx = i * 256 + tid;
        int r2 = idx >> 6, c2 = idx & 63;            // r2: n-offset, c2: k-offset
        wt[w * 32768 + (n0 + r2) * 256 + k0 + c2] = (_Float16)Ls[c2 * 65 + r2];
    }
}

// ---------------------------------------------------------------------------
// Kernel 1: projections. Y = X[16384,256] @ W[256,128] + b, f16 MFMA,
// fp32 accumulate. mode 0: q (scaled by 1/sqrt(128)*log2e), row-major.
// mode 1: k row-major. mode 2: v stored TRANSPOSED per batch: vt[b][dv][s].
// Block: 256 threads (4 waves), 64 rows x 128 cols per block.
// ---------------------------------------------------------------------------
__global__ __launch_bounds__(256) void proj_kernel(
    const float* __restrict__ xq, const float* __restrict__ xk,
    const float* __restrict__ xv, const _Float16* __restrict__ wt,
    const float* __restrict__ bq, const float* __restrict__ bk,
    const float* __restrict__ bv,
    _Float16* __restrict__ qo, _Float16* __restrict__ ko,
    _Float16* __restrict__ vt)
{
    const int mode = blockIdx.y;
    const int row0 = blockIdx.x * 64;
    const float*    X    = mode == 0 ? xq : mode == 1 ? xk : xv;
    const float*    bias = mode == 0 ? bq : mode == 1 ? bk : bv;
    const _Float16* W    = wt + mode * 32768;

    __shared__ __align__(16) _Float16 Xs[64 * 40];
    __shared__ __align__(16) _Float16 Ws[128 * 40];

    const int tid  = threadIdx.x;
    const int wave = tid >> 6, lane = tid & 63;
    const int ln   = lane & 15, qd = lane >> 4;

    f32x4 acc[8];
    #pragma unroll
    for (int i = 0; i < 8; i++) acc[i] = (f32x4){0.f, 0.f, 0.f, 0.f};

    for (int kk = 0; kk < 8; kk++) {          // K = 256 in steps of 32
        const int k0 = kk * 32;
        __syncthreads();
        #pragma unroll
        for (int i = tid; i < 512; i += 256) {
            int r = i >> 3, c = i & 7;
            f32x4 d = *(const f32x4*)(X + (size_t)(row0 + r) * 256 + k0 + c * 4);
            f16x4 h;
            h[0] = (_Float16)d[0]; h[1] = (_Float16)d[1];
            h[2] = (_Float16)d[2]; h[3] = (_Float16)d[3];
            *(f16x4*)&Xs[r * 40 + c * 4] = h;
        }
        #pragma unroll
        for (int i = tid; i < 512; i += 256) {
            int n = i >> 2, c = i & 3;
            *(u32x4*)&Ws[n * 40 + c * 8] =
                *(const u32x4*)(W + n * 256 + k0 + c * 8);
        }
        __syncthreads();
        f16x8 af = *(const f16x8*)&Xs[(wave * 16 + ln) * 40 + qd * 8];
        #pragma unroll
        for (int nt = 0; nt < 8; nt++) {
            f16x8 bf = *(const f16x8*)&Ws[(nt * 16 + ln) * 40 + qd * 8];
            acc[nt] = mfma16(af, bf, acc[nt]);
        }
    }

    const float SC = 0.08838834764831845f * 1.4426950408889634f;
    #pragma unroll
    for (int nt = 0; nt < 8; nt++) {
        int col = nt * 16 + ln;
        float bb = bias[col];
        #pragma unroll
        for (int r = 0; r < 4; r++) {
            int row = row0 + wave * 16 + qd * 4 + r;
            float val = acc[nt][r] + bb;
            if (mode == 0) {
                qo[(size_t)row * 128 + col] = (_Float16)(val * SC);
            } else if (mode == 1) {
                ko[(size_t)row * 128 + col] = (_Float16)val;
            } else {
                int b = row >> 11, s = row & 2047;
                vt[((size_t)(b * 128 + col)) * 2048 + s] = (_Float16)val;
            }
        }
    }
}

// ---------------------------------------------------------------------------
// Kernel 2: flash attention with 4-way KV split (flash-decoding style).
// Grid (32, 8, SPLIT) = 1024 blocks; block = 64 Q rows x 512 KV positions
// (8 tiles of 64). Emits unnormalized partial O (f16) + per-row (m,l) in
// log2 domain; merge_kernel combines.
// ---------------------------------------------------------------------------
__global__ __launch_bounds__(256) void attn_kernel(
    const _Float16* __restrict__ qp, const _Float16* __restrict__ kp,
    const _Float16* __restrict__ vtp, _Float16* __restrict__ opart,
    float2* __restrict__ ml)
{
    const int b  = blockIdx.y;
    const int z  = blockIdx.z;
    const int q0 = blockIdx.x * 64;
    const int tid  = threadIdx.x;
    const int wave = tid >> 6, lane = tid & 63;
    const int ln   = lane & 15, qd = lane >> 4;

    __shared__ __align__(16) _Float16 Ks[64 * 136];   // K tile [s][dk], +8 pad
    __shared__ __align__(16) _Float16 Vs[128 * 72];   // V^T tile [dv][s], +8 pad
    __shared__ __align__(16) _Float16 Ps[4 * 16 * 72];// per-wave P [16][64], +8

    const _Float16* qrow =
        qp + (size_t)(b * 2048 + q0 + wave * 16 + ln) * 128 + qd * 8;
    f16x8 qf[4];
    #pragma unroll
    for (int c = 0; c < 4; c++) qf[c] = *(const f16x8*)(qrow + c * 32);

    f32x4 o[8];
    #pragma unroll
    for (int i = 0; i < 8; i++) o[i] = (f32x4){0.f, 0.f, 0.f, 0.f};
    float m_run[4] = {-1e30f, -1e30f, -1e30f, -1e30f};
    float l_run[4] = {0.f, 0.f, 0.f, 0.f};

    const _Float16* kbase = kp + (size_t)b * 2048 * 128;
    const _Float16* vbase = vtp + (size_t)b * 128 * 2048;

    for (int kt = z * 8; kt < z * 8 + 8; kt++) {
        __syncthreads();
        const _Float16* ks = kbase + kt * 64 * 128;
        #pragma unroll
        for (int i = tid; i < 1024; i += 256) {
            int r = i >> 4, c = i & 15;
            *(u32x4*)&Ks[r * 136 + c * 8] = *(const u32x4*)(ks + r * 128 + c * 8);
        }
        const _Float16* vs = vbase + kt * 64;
        #pragma unroll
        for (int i = tid; i < 1024; i += 256) {
            int r = i >> 3, c = i & 7;
            *(u32x4*)&Vs[r * 72 + c * 8] =
                *(const u32x4*)(vs + (size_t)r * 2048 + c * 8);
        }
        __syncthreads();

        // S = Q K^T  (log2-domain: scale*log2e folded into q)
        f32x4 sc[4];
        #pragma unroll
        for (int st = 0; st < 4; st++) {
            sc[st] = (f32x4){0.f, 0.f, 0.f, 0.f};
            int base = (st * 16 + ln) * 136 + qd * 8;
            #pragma unroll
            for (int c = 0; c < 4; c++) {
                f16x8 kf = *(const f16x8*)&Ks[base + c * 32];
                sc[st] = mfma16(qf[c], kf, sc[st]);
            }
        }

        // online softmax (rows = qd*4+r, cols spread over 16 lanes)
        float mnew[4], alpha[4];
        #pragma unroll
        for (int r = 0; r < 4; r++) {
            float t = fmaxf(fmaxf(sc[0][r], sc[1][r]), fmaxf(sc[2][r], sc[3][r]));
            t = fmaxf(t, __shfl_xor(t, 1));
            t = fmaxf(t, __shfl_xor(t, 2));
            t = fmaxf(t, __shfl_xor(t, 4));
            t = fmaxf(t, __shfl_xor(t, 8));
            mnew[r]  = fmaxf(m_run[r], t);
            alpha[r] = exp2f(m_run[r] - mnew[r]);
        }
        #pragma unroll
        for (int st = 0; st < 4; st++)
            #pragma unroll
            for (int r = 0; r < 4; r++) {
                float p = exp2f(sc[st][r] - mnew[r]);
                sc[st][r] = p;
                Ps[wave * 1152 + (qd * 4 + r) * 72 + st * 16 + ln] = (_Float16)p;
            }
        #pragma unroll
        for (int r = 0; r < 4; r++) {
            float s = sc[0][r] + sc[1][r] + sc[2][r] + sc[3][r];
            s += __shfl_xor(s, 1); s += __shfl_xor(s, 2);
            s += __shfl_xor(s, 4); s += __shfl_xor(s, 8);
            l_run[r] = l_run[r] * alpha[r] + s;
            m_run[r] = mnew[r];
        }
        #pragma unroll
        for (int dt = 0; dt < 8; dt++)
            #pragma unroll
            for (int r = 0; r < 4; r++) o[dt][r] *= alpha[r];

        // O += P V
        #pragma unroll
        for (int c = 0; c < 2; c++) {
            f16x8 pf = *(const f16x8*)&Ps[wave * 1152 + ln * 72 + c * 32 + qd * 8];
            #pragma unroll
            for (int dt = 0; dt < 8; dt++) {
                f16x8 vf = *(const f16x8*)&Vs[(dt * 16 + ln) * 72 + c * 32 + qd * 8];
                o[dt] = mfma16(pf, vf, o[dt]);
            }
        }
    }

    // epilogue: write unnormalized partial O (f16) + per-row (m, l)
    const size_t prow = (size_t)(z * 8 + b) * 2048 + q0 + wave * 16;
    _Float16* op = opart + (prow + qd * 4) * 128;
    #pragma unroll
    for (int dt = 0; dt < 8; dt++)
        #pragma unroll
        for (int r = 0; r < 4; r++)
            op[(size_t)r * 128 + dt * 16 + ln] = (_Float16)o[dt][r];
    if (ln == 0) {
        #pragma unroll
        for (int r = 0; r < 4; r++) {
            float2 v; v.x = m_run[r]; v.y = l_run[r];
            ml[prow + qd * 4 + r] = v;
        }
    }
}

// ---------------------------------------------------------------------------
// Kernel 3: merge SPLIT partials. Block = 16 rows x 128 cols, grid 1024.
// ---------------------------------------------------------------------------
__global__ __launch_bounds__(256) void merge_kernel(
    const _Float16* __restrict__ opart, const float2* __restrict__ ml,
    float* __restrict__ out)
{
    const int t = threadIdx.x;
    const int r = t >> 4, cg = t & 15;
    const size_t row = (size_t)blockIdx.x * 16 + r;   // 0..16383 = b*2048+s

    float m[SPLIT], l[SPLIT], w[SPLIT];
    float M = -1e30f;
    #pragma unroll
    for (int zi = 0; zi < SPLIT; zi++) {
        // partial index layout: (z*8+b)*2048+s  ==  z*16384 + row
        float2 p = ml[(size_t)zi * 16384 + row];
        m[zi] = p.x; l[zi] = p.y; M = fmaxf(M, p.x);
    }
    float L = 0.f;
    #pragma unroll
    for (int zi = 0; zi < SPLIT; zi++) { w[zi] = exp2f(m[zi] - M); L += w[zi] * l[zi]; }
    const float inv = 1.0f / L;

    float acc[8] = {0.f, 0.f, 0.f, 0.f, 0.f, 0.f, 0.f, 0.f};
    #pragma unroll
    for (int zi = 0; zi < SPLIT; zi++) {
        f16x8 v = *(const f16x8*)&opart[((size_t)zi * 16384 + row) * 128 + cg * 8];
        #pragma unroll
        for (int j = 0; j < 8; j++) acc[j] += w[zi] * (float)v[j];
    }
    float* op = out + row * 128 + cg * 8;
    f32x4 lo = (f32x4){acc[0] * inv, acc[1] * inv, acc[2] * inv, acc[3] * inv};
    f32x4 hi = (f32x4){acc[4] * inv, acc[5] * inv, acc[6] * inv, acc[7] * inv};
    *(f32x4*)op = lo;
    *(f32x4*)(op + 4) = hi;
}

// ---------------------------------------------------------------------------
extern "C" void kernel_launch(void* const* d_in, const int* in_sizes, int n_in,
                              void* d_out, int out_size, void* d_ws, size_t ws_size,
                              hipStream_t stream) {
    const float* xq = (const float*)d_in[0];
    const float* xk = (const float*)d_in[1];
    const float* xv = (const float*)d_in[2];
    const float* Wq = (const float*)d_in[3];
    const float* bq = (const float*)d_in[4];
    const float* Wk = (const float*)d_in[5];
    const float* bk = (const float*)d_in[6];
    const float* Wv = (const float*)d_in[7];
    const float* bv = (const float*)d_in[8];
    float* out = (float*)d_out;

    // workspace layout:
    //   wt    3*128*256 f16      = 196608 B
    //   qo/ko 16384*128 f16 each = 4 MB each
    //   vt    8*128*2048 f16     = 4 MB
    //   opart SPLIT*16384*128 f16= 16 MB
    //   ml    SPLIT*16384 float2 = 512 KB
    char* ws = (char*)d_ws;
    _Float16* wt    = (_Float16*)ws;
    _Float16* qo    = (_Float16*)(ws + 196608);
    _Float16* ko    = (_Float16*)(ws + 196608 + 4194304);
    _Float16* vt    = (_Float16*)(ws + 196608 + 2 * 4194304);
    _Float16* opart = (_Float16*)(ws + 196608 + 3 * 4194304);
    float2*   ml    = (float2*)  (ws + 196608 + 3 * 4194304 + 16777216);

    hipLaunchKernelGGL(prep_weights, dim3(24), dim3(256), 0, stream,
                       Wq, Wk, Wv, wt);
    hipLaunchKernelGGL(proj_kernel, dim3(256, 3), dim3(256), 0, stream,
                       xq, xk, xv, wt, bq, bk, bv, qo, ko, vt);
    hipLaunchKernelGGL(attn_kernel, dim3(32, 8, SPLIT), dim3(256), 0, stream,
                       qo, ko, vt, opart, ml);
    hipLaunchKernelGGL(merge_kernel, dim3(1024), dim3(256), 0, stream,
                       opart, ml, out);
}

// Round 3
// 175.321 us; speedup vs baseline: 1.3290x; 1.0818x over previous
//
#include <hip/hip_runtime.h>
#include <stdint.h>

// Problem constants: B=8, S=2048, D=256, DK=DV=128
typedef float    f32x4 __attribute__((ext_vector_type(4)));
typedef _Float16 f16x8 __attribute__((ext_vector_type(8)));
typedef _Float16 f16x4 __attribute__((ext_vector_type(4)));
typedef unsigned int u32x4 __attribute__((ext_vector_type(4)));

#define SPLIT 4   // KV splits per (batch, q-tile); 2048/SPLIT = 512 keys/block

__device__ __forceinline__ f32x4 mfma16(f16x8 a, f16x8 b, f32x4 c) {
    return __builtin_amdgcn_mfma_f32_16x16x32_f16(a, b, c, 0, 0, 0);
}

// ---------------------------------------------------------------------------
// Kernel 0: transpose+convert W[256][128] f32 -> Wt[w][n][k]=[3][128][256] f16
// via LDS 64x64 tiles: coalesced global reads AND writes.
// ---------------------------------------------------------------------------
__global__ __launch_bounds__(256) void prep_weights(
    const float* __restrict__ Wq, const float* __restrict__ Wk,
    const float* __restrict__ Wv, _Float16* __restrict__ wt) {
    __shared__ float Ls[64 * 65];
    const int bx = blockIdx.x;
    const int w  = bx >> 3, t = bx & 7;
    const int k0 = (t >> 1) * 64, n0 = (t & 1) * 64;
    const float* W = (w == 0) ? Wq : (w == 1) ? Wk : Wv;
    const int tid = threadIdx.x;
    #pragma unroll
    for (int i = 0; i < 16; i++) {
        int idx = i * 256 + tid;
        int r = idx >> 6, c = idx & 63;
        Ls[r * 65 + c] = W[(k0 + r) * 128 + n0 + c];
    }
    __syncthreads();
    #pragma unroll
    for (int i = 0; i < 16; i++) {
        int idx = i * 256 + tid;
        int r2 = idx >> 6, c2 = idx & 63;
        wt[w * 32768 + (n0 + r2) * 256 + k0 + c2] = (_Float16)Ls[c2 * 65 + r2];
    }
}

// ---------------------------------------------------------------------------
// Kernel 1: projections, BARRIER-FREE / LDS-FREE. Y = X@W + b, f16 MFMA.
// A-frags loaded directly from global f32 (cvt in reg); B-frags directly from
// pre-transposed f16 weights (64 KB per mode -> L1/L2-resident). All modes
// write row-major [row][128] coalesced; V transposed by a separate kernel.
// Block: 256 threads = 4 waves, each wave 16 rows x 128 cols.
// ---------------------------------------------------------------------------
__global__ __launch_bounds__(256) void proj_kernel(
    const float* __restrict__ xq, const float* __restrict__ xk,
    const float* __restrict__ xv, const _Float16* __restrict__ wt,
    const float* __restrict__ bq, const float* __restrict__ bk,
    const float* __restrict__ bv,
    _Float16* __restrict__ qo, _Float16* __restrict__ ko,
    _Float16* __restrict__ vtmp)
{
    const int mode = blockIdx.y;
    const float*    X    = mode == 0 ? xq : mode == 1 ? xk : xv;
    const float*    bias = mode == 0 ? bq : mode == 1 ? bk : bv;
    const _Float16* W    = wt + mode * 32768;
    _Float16*       Y    = mode == 0 ? qo : mode == 1 ? ko : vtmp;

    const int tid  = threadIdx.x;
    const int wave = tid >> 6, lane = tid & 63;
    const int ln   = lane & 15, qd = lane >> 4;
    const int row0 = blockIdx.x * 64 + wave * 16;

    const float*    xrow = X + (size_t)(row0 + ln) * 256 + qd * 8;
    const _Float16* wb   = W + ln * 256 + qd * 8;

    f32x4 acc[8];
    #pragma unroll
    for (int i = 0; i < 8; i++) acc[i] = (f32x4){0.f, 0.f, 0.f, 0.f};

    #pragma unroll
    for (int kk = 0; kk < 8; kk++) {          // K = 256 in steps of 32
        f32x4 a0 = *(const f32x4*)(xrow + kk * 32);
        f32x4 a1 = *(const f32x4*)(xrow + kk * 32 + 4);
        f16x8 af;
        af[0] = (_Float16)a0[0]; af[1] = (_Float16)a0[1];
        af[2] = (_Float16)a0[2]; af[3] = (_Float16)a0[3];
        af[4] = (_Float16)a1[0]; af[5] = (_Float16)a1[1];
        af[6] = (_Float16)a1[2]; af[7] = (_Float16)a1[3];
        #pragma unroll
        for (int nt = 0; nt < 8; nt++) {
            f16x8 bf = *(const f16x8*)(wb + nt * 4096 + kk * 32);
            acc[nt] = mfma16(af, bf, acc[nt]);
        }
    }

    const float SC = 0.08838834764831845f * 1.4426950408889634f;
    #pragma unroll
    for (int nt = 0; nt < 8; nt++) {
        int col = nt * 16 + ln;
        float bb = bias[col];
        #pragma unroll
        for (int r = 0; r < 4; r++) {
            int orow = row0 + qd * 4 + r;         // C/D: row=(lane>>4)*4+r
            float val = acc[nt][r] + bb;
            if (mode == 0) val *= SC;
            Y[(size_t)orow * 128 + col] = (_Float16)val;
        }
    }
}

// ---------------------------------------------------------------------------
// Kernel 1b: transpose V: vtmp[b][s][128] -> vt[b][128][2048], LDS 64x64
// tiles, coalesced both directions. Grid (32, 2, 8).
// ---------------------------------------------------------------------------
__global__ __launch_bounds__(256) void transpose_v(
    const _Float16* __restrict__ vtmp, _Float16* __restrict__ vt)
{
    __shared__ __align__(16) _Float16 Ls[64 * 72];
    const int b  = blockIdx.z;
    const int s0 = blockIdx.x * 64;
    const int d0 = blockIdx.y * 64;
    const int tid = threadIdx.x;
    #pragma unroll
    for (int i = 0; i < 2; i++) {
        int idx = i * 256 + tid;
        int r = idx >> 3, c = (idx & 7) * 8;      // r: s-off, c: d-off
        *(f16x8*)&Ls[r * 72 + c] =
            *(const f16x8*)(vtmp + (size_t)(b * 2048 + s0 + r) * 128 + d0 + c);
    }
    __syncthreads();
    #pragma unroll
    for (int i = 0; i < 2; i++) {
        int idx = i * 256 + tid;
        int dr = idx >> 3, sc8 = (idx & 7) * 8;   // dr: d-off, sc8: s-off
        f16x8 o;
        #pragma unroll
        for (int j = 0; j < 8; j++) o[j] = Ls[(sc8 + j) * 72 + dr];
        *(f16x8*)(vt + (size_t)(b * 128 + d0 + dr) * 2048 + s0 + sc8) = o;
    }
}

// ---------------------------------------------------------------------------
// Kernel 2: flash attention, 4-way KV split. Block = 512 threads (8 waves),
// 128 Q rows x 512 KV positions (8 tiles of 64) sharing one K/V staging.
// LDS 54272 B -> 2 blocks/CU resident (16 waves/CU) in a single round.
// Grid (16, 8, SPLIT) = 512 blocks.
// ---------------------------------------------------------------------------
__global__ __launch_bounds__(512, 4) void attn_kernel(
    const _Float16* __restrict__ qp, const _Float16* __restrict__ kp,
    const _Float16* __restrict__ vtp, _Float16* __restrict__ opart,
    float2* __restrict__ ml)
{
    const int b  = blockIdx.y;
    const int z  = blockIdx.z;
    const int q0 = blockIdx.x * 128;
    const int tid  = threadIdx.x;
    const int wave = tid >> 6, lane = tid & 63;
    const int ln   = lane & 15, qd = lane >> 4;

    __shared__ __align__(16) _Float16 Ks[64 * 136];    // K tile [s][dk], +8 pad
    __shared__ __align__(16) _Float16 Vs[128 * 72];    // V^T tile [dv][s], +8 pad
    __shared__ __align__(16) _Float16 Ps[8 * 16 * 72]; // per-wave P [16][64], +8

    const _Float16* qrow =
        qp + (size_t)(b * 2048 + q0 + wave * 16 + ln) * 128 + qd * 8;
    f16x8 qf[4];
    #pragma unroll
    for (int c = 0; c < 4; c++) qf[c] = *(const f16x8*)(qrow + c * 32);

    f32x4 o[8];
    #pragma unroll
    for (int i = 0; i < 8; i++) o[i] = (f32x4){0.f, 0.f, 0.f, 0.f};
    float m_run[4] = {-1e30f, -1e30f, -1e30f, -1e30f};
    float l_run[4] = {0.f, 0.f, 0.f, 0.f};

    const _Float16* kbase = kp + (size_t)b * 2048 * 128;
    const _Float16* vbase = vtp + (size_t)b * 128 * 2048;

    for (int kt = z * 8; kt < z * 8 + 8; kt++) {
        __syncthreads();
        const _Float16* ks = kbase + kt * 64 * 128;
        #pragma unroll
        for (int i = tid; i < 1024; i += 512) {
            int r = i >> 4, c = i & 15;
            *(u32x4*)&Ks[r * 136 + c * 8] = *(const u32x4*)(ks + r * 128 + c * 8);
        }
        const _Float16* vs = vbase + kt * 64;
        #pragma unroll
        for (int i = tid; i < 1024; i += 512) {
            int r = i >> 3, c = i & 7;
            *(u32x4*)&Vs[r * 72 + c * 8] =
                *(const u32x4*)(vs + (size_t)r * 2048 + c * 8);
        }
        __syncthreads();

        // S = Q K^T  (log2-domain: scale*log2e folded into q)
        f32x4 sc[4];
        #pragma unroll
        for (int st = 0; st < 4; st++) {
            sc[st] = (f32x4){0.f, 0.f, 0.f, 0.f};
            int base = (st * 16 + ln) * 136 + qd * 8;
            #pragma unroll
            for (int c = 0; c < 4; c++) {
                f16x8 kf = *(const f16x8*)&Ks[base + c * 32];
                sc[st] = mfma16(qf[c], kf, sc[st]);
            }
        }

        // online softmax (rows = qd*4+r, cols spread over 16 lanes)
        float mnew[4], alpha[4];
        #pragma unroll
        for (int r = 0; r < 4; r++) {
            float t = fmaxf(fmaxf(sc[0][r], sc[1][r]), fmaxf(sc[2][r], sc[3][r]));
            t = fmaxf(t, __shfl_xor(t, 1));
            t = fmaxf(t, __shfl_xor(t, 2));
            t = fmaxf(t, __shfl_xor(t, 4));
            t = fmaxf(t, __shfl_xor(t, 8));
            mnew[r]  = fmaxf(m_run[r], t);
            alpha[r] = exp2f(m_run[r] - mnew[r]);
        }
        #pragma unroll
        for (int st = 0; st < 4; st++)
            #pragma unroll
            for (int r = 0; r < 4; r++) {
                float p = exp2f(sc[st][r] - mnew[r]);
                sc[st][r] = p;
                Ps[wave * 1152 + (qd * 4 + r) * 72 + st * 16 + ln] = (_Float16)p;
            }
        #pragma unroll
        for (int r = 0; r < 4; r++) {
            float s = sc[0][r] + sc[1][r] + sc[2][r] + sc[3][r];
            s += __shfl_xor(s, 1); s += __shfl_xor(s, 2);
            s += __shfl_xor(s, 4); s += __shfl_xor(s, 8);
            l_run[r] = l_run[r] * alpha[r] + s;
            m_run[r] = mnew[r];
        }
        #pragma unroll
        for (int dt = 0; dt < 8; dt++)
            #pragma unroll
            for (int r = 0; r < 4; r++) o[dt][r] *= alpha[r];

        // O += P V
        #pragma unroll
        for (int c = 0; c < 2; c++) {
            f16x8 pf = *(const f16x8*)&Ps[wave * 1152 + ln * 72 + c * 32 + qd * 8];
            #pragma unroll
            for (int dt = 0; dt < 8; dt++) {
                f16x8 vf = *(const f16x8*)&Vs[(dt * 16 + ln) * 72 + c * 32 + qd * 8];
                o[dt] = mfma16(pf, vf, o[dt]);
            }
        }
    }

    // epilogue: write unnormalized partial O (f16) + per-row (m, l)
    const size_t prow = (size_t)(z * 8 + b) * 2048 + q0 + wave * 16;
    _Float16* op = opart + (prow + qd * 4) * 128;
    #pragma unroll
    for (int dt = 0; dt < 8; dt++)
        #pragma unroll
        for (int r = 0; r < 4; r++)
            op[(size_t)r * 128 + dt * 16 + ln] = (_Float16)o[dt][r];
    if (ln == 0) {
        #pragma unroll
        for (int r = 0; r < 4; r++) {
            float2 v; v.x = m_run[r]; v.y = l_run[r];
            ml[prow + qd * 4 + r] = v;
        }
    }
}

// ---------------------------------------------------------------------------
// Kernel 3: merge SPLIT partials. Block = 16 rows x 128 cols, grid 1024.
// ---------------------------------------------------------------------------
__global__ __launch_bounds__(256) void merge_kernel(
    const _Float16* __restrict__ opart, const float2* __restrict__ ml,
    float* __restrict__ out)
{
    const int t = threadIdx.x;
    const int r = t >> 4, cg = t & 15;
    const size_t row = (size_t)blockIdx.x * 16 + r;   // 0..16383 = b*2048+s

    float m[SPLIT], l[SPLIT], w[SPLIT];
    float M = -1e30f;
    #pragma unroll
    for (int zi = 0; zi < SPLIT; zi++) {
        float2 p = ml[(size_t)zi * 16384 + row];
        m[zi] = p.x; l[zi] = p.y; M = fmaxf(M, p.x);
    }
    float L = 0.f;
    #pragma unroll
    for (int zi = 0; zi < SPLIT; zi++) { w[zi] = exp2f(m[zi] - M); L += w[zi] * l[zi]; }
    const float inv = 1.0f / L;

    float acc[8] = {0.f, 0.f, 0.f, 0.f, 0.f, 0.f, 0.f, 0.f};
    #pragma unroll
    for (int zi = 0; zi < SPLIT; zi++) {
        f16x8 v = *(const f16x8*)&opart[((size_t)zi * 16384 + row) * 128 + cg * 8];
        #pragma unroll
        for (int j = 0; j < 8; j++) acc[j] += w[zi] * (float)v[j];
    }
    float* op = out + row * 128 + cg * 8;
    f32x4 lo = (f32x4){acc[0] * inv, acc[1] * inv, acc[2] * inv, acc[3] * inv};
    f32x4 hi = (f32x4){acc[4] * inv, acc[5] * inv, acc[6] * inv, acc[7] * inv};
    *(f32x4*)op = lo;
    *(f32x4*)(op + 4) = hi;
}

// ---------------------------------------------------------------------------
extern "C" void kernel_launch(void* const* d_in, const int* in_sizes, int n_in,
                              void* d_out, int out_size, void* d_ws, size_t ws_size,
                              hipStream_t stream) {
    const float* xq = (const float*)d_in[0];
    const float* xk = (const float*)d_in[1];
    const float* xv = (const float*)d_in[2];
    const float* Wq = (const float*)d_in[3];
    const float* bq = (const float*)d_in[4];
    const float* Wk = (const float*)d_in[5];
    const float* bk = (const float*)d_in[6];
    const float* Wv = (const float*)d_in[7];
    const float* bv = (const float*)d_in[8];
    float* out = (float*)d_out;

    // workspace layout:
    //   wt    3*128*256 f16       = 196608 B
    //   qo/ko 16384*128 f16 each  = 4 MB each
    //   vt    8*128*2048 f16      = 4 MB
    //   opart SPLIT*16384*128 f16 = 16 MB  (vtmp aliases this region:
    //         vtmp is consumed by transpose_v BEFORE attn writes opart)
    //   ml    SPLIT*16384 float2  = 512 KB
    char* ws = (char*)d_ws;
    _Float16* wt    = (_Float16*)ws;
    _Float16* qo    = (_Float16*)(ws + 196608);
    _Float16* ko    = (_Float16*)(ws + 196608 + 4194304);
    _Float16* vt    = (_Float16*)(ws + 196608 + 2 * 4194304);
    _Float16* opart = (_Float16*)(ws + 196608 + 3 * 4194304);
    _Float16* vtmp  = opart;   // alias, lifetime disjoint
    float2*   ml    = (float2*)  (ws + 196608 + 3 * 4194304 + 16777216);

    hipLaunchKernelGGL(prep_weights, dim3(24), dim3(256), 0, stream,
                       Wq, Wk, Wv, wt);
    hipLaunchKernelGGL(proj_kernel, dim3(256, 3), dim3(256), 0, stream,
                       xq, xk, xv, wt, bq, bk, bv, qo, ko, vtmp);
    hipLaunchKernelGGL(transpose_v, dim3(32, 2, 8), dim3(256), 0, stream,
                       vtmp, vt);
    hipLaunchKernelGGL(attn_kernel, dim3(16, 8, SPLIT), dim3(512), 0, stream,
                       qo, ko, vt, opart, ml);
    hipLaunchKernelGGL(merge_kernel, dim3(1024), dim3(256), 0, stream,
                       opart, ml, out);
}